// Round 1
// baseline (10527.505 us; speedup 1.0000x reference)
//
#include <hip/hip_runtime.h>
#include <math.h>

// ODE-RNN forward: B=1024, T=100, D=32, H=256, MID=50 (padded 64), RK4x4.
// One persistent kernel; block = 256 threads = 4 waves, owns 4 batch rows
// for the whole T loop (rows are independent -> no inter-block sync).
// ODE weights live in LDS (reused 16x/step); once-per-step weights stream
// from L2 pre-transposed (coalesced: lane = output neuron).

#define NT 256

// ---------------- ws layout (floats) ----------------
#define WS_WIHT 0        // [32][256]
#define WS_WHHT 8192     // [256][256]
#define WS_L1WT 73728    // [256][128]
#define WS_SW1T 106496   // [256][256]
#define WS_TOT  172032

// ---------------- LDS layout (floats) ----------------
#define SM_W1T 0         // [256][64]  ode_w1^T, cols 50..63 zero
#define SM_W2T 16384     // [64][256]  ode_w2^T, rows 50..63 zero
#define SM_H   32768     // [4][256]
#define SM_YC  33792     // [4][256]   (aliased as l1o[4][128] in heads)
#define SM_AC  34816     // [4][256]   (aliased as sg[4][256] in heads)
#define SM_MD  35840     // [4][64]
#define SM_RD  36096     // [4][4][64] / [2][4][128] partial-reduce scratch
#define SM_XS  37120     // [4][32]
#define SM_BC  37248     // [256] b_ih+b_hh
#define SM_OB1 37504     // [64]
#define SM_OB2 37568     // [256]
#define SM_L1B 37824     // [128]
#define SM_SB1 37952     // [256]
#define SM_MUW 38208     // [128]
#define SM_SW2 38336     // [256]
#define SM_SCL 38592     // [4]
#define SM_TOT 38596
#define SMEM_BYTES (SM_TOT * 4)

__global__ void prep_transpose(const float* __restrict__ Wih,
                               const float* __restrict__ Whh,
                               const float* __restrict__ l1w,
                               const float* __restrict__ sw1,
                               float* __restrict__ ws) {
  int i = blockIdx.x * NT + threadIdx.x;
  if (i < 8192) {                          // WihT[k][j] = Wih[j][k], [32][256]
    int k = i >> 8, j = i & 255;
    ws[WS_WIHT + i] = Wih[j * 32 + k];
  } else if (i < 73728) {                  // WhhT[k][j], [256][256]
    int t = i - 8192; int k = t >> 8, j = t & 255;
    ws[i] = Whh[j * 256 + k];
  } else if (i < 106496) {                 // l1wT[k][j], [256][128]
    int t = i - 73728; int k = t >> 7, j = t & 127;
    ws[i] = l1w[j * 256 + k];
  } else if (i < WS_TOT) {                 // sw1T[k][j], [256][256]
    int t = i - 106496; int k = t >> 8, j = t & 255;
    ws[i] = sw1[j * 256 + k];
  }
}

__launch_bounds__(NT, 1)
__global__ void odernn_main(const float* __restrict__ dt,
                            const float* __restrict__ x,
                            const float* __restrict__ bih,
                            const float* __restrict__ bhh,
                            const float* __restrict__ ow1,
                            const float* __restrict__ ob1g,
                            const float* __restrict__ ow2,
                            const float* __restrict__ ob2g,
                            const float* __restrict__ l1bg,
                            const float* __restrict__ muwg,
                            const float* __restrict__ mubg,
                            const float* __restrict__ sb1g,
                            const float* __restrict__ sw2g,
                            const float* __restrict__ sb2g,
                            const float* __restrict__ ws,
                            float* __restrict__ out) {
  extern __shared__ __align__(16) float sm[];
  const int tid = threadIdx.x;
  const int wv = tid >> 6, ln = tid & 63;
  const int b0 = blockIdx.x * 4;

  float* w1T = sm + SM_W1T;
  float* w2T = sm + SM_W2T;
  float* hS  = sm + SM_H;
  float* ycS = sm + SM_YC;
  float* acS = sm + SM_AC;
  float* mdS = sm + SM_MD;
  float* rdS = sm + SM_RD;
  float* xsS = sm + SM_XS;
  float* bcS = sm + SM_BC;
  float* ob1S = sm + SM_OB1;
  float* ob2S = sm + SM_OB2;
  float* l1bS = sm + SM_L1B;
  float* sb1S = sm + SM_SB1;
  float* muwS = sm + SM_MUW;
  float* sw2S = sm + SM_SW2;
  float* sclS = sm + SM_SCL;
  float* l1oS = ycS;   // heads-phase alias
  float* sgS  = acS;   // heads-phase alias

  const float* WihT = ws + WS_WIHT;
  const float* WhhT = ws + WS_WHHT;
  const float* l1wT = ws + WS_L1WT;
  const float* sw1T = ws + WS_SW1T;

  // ---- one-time staging
  for (int i = tid; i < 16384; i += NT) {     // w1T[k][j] (j<50 real)
    int k = i >> 6, j = i & 63;
    w1T[i] = (j < 50) ? ow1[j * 256 + k] : 0.f;
  }
  for (int i = tid; i < 16384; i += NT) {     // w2T[k][j] (k<50 real)
    int k = i >> 8, j = i & 255;
    w2T[i] = (k < 50) ? ow2[j * 50 + k] : 0.f;
  }
  bcS[tid]  = bih[tid] + bhh[tid];
  ob2S[tid] = ob2g[tid];
  sb1S[tid] = sb1g[tid];
  sw2S[tid] = sw2g[tid];
  if (tid < 64)  ob1S[tid] = (tid < 50) ? ob1g[tid] : 0.f;
  if (tid < 128) { l1bS[tid] = l1bg[tid]; muwS[tid] = muwg[tid]; }
  hS[0 * 256 + tid] = 0.f; hS[1 * 256 + tid] = 0.f;
  hS[2 * 256 + tid] = 0.f; hS[3 * 256 + tid] = 0.f;
  __syncthreads();

  const float mub = mubg[0], sb2 = sb2g[0];

  for (int t = 0; t < 100; ++t) {
    // ---- stage x tile and per-row scale
    if (tid < 128) {
      int r = tid >> 5, k = tid & 31;
      xsS[r * 32 + k] = x[((size_t)(b0 + r) * 100 + t) * 32 + k];
    }
    if (tid < 4) {
      const float* dp = dt + ((size_t)(b0 + tid) * 100 + t) * 2;
      sclS[tid] = (dp[1] - dp[0]) * (1.f / 24.f);
    }
    __syncthreads();

    // ===== RNN cell: h += tanh(x@WihT + h@WhhT + (b_ih+b_hh))
    {
      const int j = tid;
      float a0 = bcS[j], a1 = a0, a2 = a0, a3 = a0;
#pragma unroll
      for (int k = 0; k < 32; k += 4) {
        float w0 = WihT[(k + 0) * 256 + j], w1 = WihT[(k + 1) * 256 + j];
        float w2 = WihT[(k + 2) * 256 + j], w3 = WihT[(k + 3) * 256 + j];
        float4 p0 = *(const float4*)&xsS[0 * 32 + k];
        float4 p1 = *(const float4*)&xsS[1 * 32 + k];
        float4 p2 = *(const float4*)&xsS[2 * 32 + k];
        float4 p3 = *(const float4*)&xsS[3 * 32 + k];
        a0 += p0.x * w0 + p0.y * w1 + p0.z * w2 + p0.w * w3;
        a1 += p1.x * w0 + p1.y * w1 + p1.z * w2 + p1.w * w3;
        a2 += p2.x * w0 + p2.y * w1 + p2.z * w2 + p2.w * w3;
        a3 += p3.x * w0 + p3.y * w1 + p3.z * w2 + p3.w * w3;
      }
#pragma unroll 2
      for (int k = 0; k < 256; k += 4) {
        float w0 = WhhT[(k + 0) * 256 + j], w1 = WhhT[(k + 1) * 256 + j];
        float w2 = WhhT[(k + 2) * 256 + j], w3 = WhhT[(k + 3) * 256 + j];
        float4 p0 = *(const float4*)&hS[0 * 256 + k];
        float4 p1 = *(const float4*)&hS[1 * 256 + k];
        float4 p2 = *(const float4*)&hS[2 * 256 + k];
        float4 p3 = *(const float4*)&hS[3 * 256 + k];
        a0 += p0.x * w0 + p0.y * w1 + p0.z * w2 + p0.w * w3;
        a1 += p1.x * w0 + p1.y * w1 + p1.z * w2 + p1.w * w3;
        a2 += p2.x * w0 + p2.y * w1 + p2.z * w2 + p2.w * w3;
        a3 += p3.x * w0 + p3.y * w1 + p3.z * w2 + p3.w * w3;
      }
      __syncthreads();             // all h reads done
      hS[0 * 256 + j] += tanhf(a0);
      hS[1 * 256 + j] += tanhf(a1);
      hS[2 * 256 + j] += tanhf(a2);
      hS[3 * 256 + j] += tanhf(a3);
      __syncthreads();
    }

    const float s0c = sclS[0], s1c = sclS[1], s2c = sclS[2], s3c = sclS[3];

    // ===== ODE: 4 RK4 steps, hs = 0.25
#pragma unroll 1
    for (int os = 0; os < 4; ++os) {
      ycS[0 * 256 + tid] = hS[0 * 256 + tid];
      ycS[1 * 256 + tid] = hS[1 * 256 + tid];
      ycS[2 * 256 + tid] = hS[2 * 256 + tid];
      ycS[3 * 256 + tid] = hS[3 * 256 + tid];
      __syncthreads();
#pragma unroll 1
      for (int s = 0; s < 4; ++s) {
        // --- layer1 partials: wave wv owns k-chunk, lane ln = mid neuron
        {
          float a0 = 0.f, a1 = 0.f, a2 = 0.f, a3 = 0.f;
          const int kb = wv * 64;
#pragma unroll 4
          for (int kk = 0; kk < 64; kk += 4) {
            int k = kb + kk;
            float w0 = w1T[(k + 0) * 64 + ln], w1 = w1T[(k + 1) * 64 + ln];
            float w2 = w1T[(k + 2) * 64 + ln], w3 = w1T[(k + 3) * 64 + ln];
            float4 y0 = *(const float4*)&ycS[0 * 256 + k];
            float4 y1 = *(const float4*)&ycS[1 * 256 + k];
            float4 y2 = *(const float4*)&ycS[2 * 256 + k];
            float4 y3 = *(const float4*)&ycS[3 * 256 + k];
            a0 += y0.x * w0 + y0.y * w1 + y0.z * w2 + y0.w * w3;
            a1 += y1.x * w0 + y1.y * w1 + y1.z * w2 + y1.w * w3;
            a2 += y2.x * w0 + y2.y * w1 + y2.z * w2 + y2.w * w3;
            a3 += y3.x * w0 + y3.y * w1 + y3.z * w2 + y3.w * w3;
          }
          rdS[(wv * 4 + 0) * 64 + ln] = a0;
          rdS[(wv * 4 + 1) * 64 + ln] = a1;
          rdS[(wv * 4 + 2) * 64 + ln] = a2;
          rdS[(wv * 4 + 3) * 64 + ln] = a3;
        }
        __syncthreads();
        // --- reduce + tanh: wave wv owns row wv (padded mid 50..63 -> 0)
        {
          float sv = rdS[(0 * 4 + wv) * 64 + ln] + rdS[(1 * 4 + wv) * 64 + ln]
                   + rdS[(2 * 4 + wv) * 64 + ln] + rdS[(3 * 4 + wv) * 64 + ln];
          mdS[wv * 64 + ln] = tanhf(sv + ob1S[ln]);
        }
        __syncthreads();
        // --- layer2 + RK4 update: thread owns column j across 4 rows
        {
          const int j = tid;
          float k0 = ob2S[j], k1 = k0, k2 = k0, k3 = k0;
#pragma unroll 4
          for (int k = 0; k < 64; k += 4) {
            float w0 = w2T[(k + 0) * 256 + j], w1 = w2T[(k + 1) * 256 + j];
            float w2 = w2T[(k + 2) * 256 + j], w3 = w2T[(k + 3) * 256 + j];
            float4 m0 = *(const float4*)&mdS[0 * 64 + k];
            float4 m1 = *(const float4*)&mdS[1 * 64 + k];
            float4 m2 = *(const float4*)&mdS[2 * 64 + k];
            float4 m3 = *(const float4*)&mdS[3 * 64 + k];
            k0 += m0.x * w0 + m0.y * w1 + m0.z * w2 + m0.w * w3;
            k1 += m1.x * w0 + m1.y * w1 + m1.z * w2 + m1.w * w3;
            k2 += m2.x * w0 + m2.y * w1 + m2.z * w2 + m2.w * w3;
            k3 += m3.x * w0 + m3.y * w1 + m3.z * w2 + m3.w * w3;
          }
          k0 *= s0c; k1 *= s1c; k2 *= s2c; k3 *= s3c;
          if (s == 0) {
            acS[0 * 256 + j] = k0; ycS[0 * 256 + j] = hS[0 * 256 + j] + 0.125f * k0;
            acS[1 * 256 + j] = k1; ycS[1 * 256 + j] = hS[1 * 256 + j] + 0.125f * k1;
            acS[2 * 256 + j] = k2; ycS[2 * 256 + j] = hS[2 * 256 + j] + 0.125f * k2;
            acS[3 * 256 + j] = k3; ycS[3 * 256 + j] = hS[3 * 256 + j] + 0.125f * k3;
          } else if (s == 1) {
            acS[0 * 256 + j] += 2.f * k0; ycS[0 * 256 + j] = hS[0 * 256 + j] + 0.125f * k0;
            acS[1 * 256 + j] += 2.f * k1; ycS[1 * 256 + j] = hS[1 * 256 + j] + 0.125f * k1;
            acS[2 * 256 + j] += 2.f * k2; ycS[2 * 256 + j] = hS[2 * 256 + j] + 0.125f * k2;
            acS[3 * 256 + j] += 2.f * k3; ycS[3 * 256 + j] = hS[3 * 256 + j] + 0.125f * k3;
          } else if (s == 2) {
            acS[0 * 256 + j] += 2.f * k0; ycS[0 * 256 + j] = hS[0 * 256 + j] + 0.25f * k0;
            acS[1 * 256 + j] += 2.f * k1; ycS[1 * 256 + j] = hS[1 * 256 + j] + 0.25f * k1;
            acS[2 * 256 + j] += 2.f * k2; ycS[2 * 256 + j] = hS[2 * 256 + j] + 0.25f * k2;
            acS[3 * 256 + j] += 2.f * k3; ycS[3 * 256 + j] = hS[3 * 256 + j] + 0.25f * k3;
          } else {
            hS[0 * 256 + j] += (0.25f / 6.f) * (acS[0 * 256 + j] + k0);
            hS[1 * 256 + j] += (0.25f / 6.f) * (acS[1 * 256 + j] + k1);
            hS[2 * 256 + j] += (0.25f / 6.f) * (acS[2 * 256 + j] + k2);
            hS[3 * 256 + j] += (0.25f / 6.f) * (acS[3 * 256 + j] + k3);
          }
        }
        __syncthreads();
      }
    }

    // ===== heads
    // l1 partials: j2 = tid&127, kc = tid>>7 (2-way K split)
    {
      const int j2 = tid & 127, kc = tid >> 7;
      float a0 = 0.f, a1 = 0.f, a2 = 0.f, a3 = 0.f;
      const int kb = kc * 128;
#pragma unroll 2
      for (int kk = 0; kk < 128; kk += 4) {
        int k = kb + kk;
        float w0 = l1wT[(k + 0) * 128 + j2], w1 = l1wT[(k + 1) * 128 + j2];
        float w2 = l1wT[(k + 2) * 128 + j2], w3 = l1wT[(k + 3) * 128 + j2];
        float4 h0 = *(const float4*)&hS[0 * 256 + k];
        float4 h1 = *(const float4*)&hS[1 * 256 + k];
        float4 h2 = *(const float4*)&hS[2 * 256 + k];
        float4 h3 = *(const float4*)&hS[3 * 256 + k];
        a0 += h0.x * w0 + h0.y * w1 + h0.z * w2 + h0.w * w3;
        a1 += h1.x * w0 + h1.y * w1 + h1.z * w2 + h1.w * w3;
        a2 += h2.x * w0 + h2.y * w1 + h2.z * w2 + h2.w * w3;
        a3 += h3.x * w0 + h3.y * w1 + h3.z * w2 + h3.w * w3;
      }
      rdS[(kc * 4 + 0) * 128 + j2] = a0;
      rdS[(kc * 4 + 1) * 128 + j2] = a1;
      rdS[(kc * 4 + 2) * 128 + j2] = a2;
      rdS[(kc * 4 + 3) * 128 + j2] = a3;
    }
    __syncthreads();
    // l1o = relu(partial0+partial1+b): 512 slots, 2 per thread
    {
      int s1i = tid, s2i = tid + 256;
      int r1 = s1i >> 7, j1 = s1i & 127;
      int r2 = s2i >> 7, j2 = s2i & 127;
      float v1 = rdS[(0 + r1) * 128 + j1] + rdS[(4 + r1) * 128 + j1] + l1bS[j1];
      float v2 = rdS[(0 + r2) * 128 + j2] + rdS[(4 + r2) * 128 + j2] + l1bS[j2];
      l1oS[r1 * 128 + j1] = fmaxf(v1, 0.f);
      l1oS[r2 * 128 + j2] = fmaxf(v2, 0.f);
    }
    // sig1: thread owns column j, 4 rows
    {
      const int j = tid;
      float a0 = sb1S[j], a1 = a0, a2 = a0, a3 = a0;
#pragma unroll 2
      for (int k = 0; k < 256; k += 4) {
        float w0 = sw1T[(k + 0) * 256 + j], w1 = sw1T[(k + 1) * 256 + j];
        float w2 = sw1T[(k + 2) * 256 + j], w3 = sw1T[(k + 3) * 256 + j];
        float4 h0 = *(const float4*)&hS[0 * 256 + k];
        float4 h1 = *(const float4*)&hS[1 * 256 + k];
        float4 h2 = *(const float4*)&hS[2 * 256 + k];
        float4 h3 = *(const float4*)&hS[3 * 256 + k];
        a0 += h0.x * w0 + h0.y * w1 + h0.z * w2 + h0.w * w3;
        a1 += h1.x * w0 + h1.y * w1 + h1.z * w2 + h1.w * w3;
        a2 += h2.x * w0 + h2.y * w1 + h2.z * w2 + h2.w * w3;
        a3 += h3.x * w0 + h3.y * w1 + h3.z * w2 + h3.w * w3;
      }
      sgS[0 * 256 + j] = tanhf(a0);
      sgS[1 * 256 + j] = tanhf(a1);
      sgS[2 * 256 + j] = tanhf(a2);
      sgS[3 * 256 + j] = tanhf(a3);
    }
    __syncthreads();
    // final dot-products: wave wv owns row wv
    {
      const int r = wv;
      float pm = l1oS[r * 128 + ln] * muwS[ln]
               + l1oS[r * 128 + 64 + ln] * muwS[64 + ln];
      float ps = sgS[r * 256 + ln] * sw2S[ln]
               + sgS[r * 256 + 64 + ln] * sw2S[64 + ln]
               + sgS[r * 256 + 128 + ln] * sw2S[128 + ln]
               + sgS[r * 256 + 192 + ln] * sw2S[192 + ln];
#pragma unroll
      for (int off = 32; off > 0; off >>= 1) {
        pm += __shfl_down(pm, off);
        ps += __shfl_down(ps, off);
      }
      if (ln == 0) {
        float m = pm + mub;
        float z = ps + sb2;
        float sp = fmaxf(z, 0.f) + log1pf(expf(-fabsf(z)));
        out[(size_t)(b0 + r) * 100 + t] = m;
        out[(size_t)102400 + (size_t)(b0 + r) * 100 + t] = sp;
      }
    }
    __syncthreads();
  }
}

extern "C" void kernel_launch(void* const* d_in, const int* in_sizes, int n_in,
                              void* d_out, int out_size, void* d_ws, size_t ws_size,
                              hipStream_t stream) {
  const float* dt  = (const float*)d_in[0];
  const float* x   = (const float*)d_in[1];
  const float* Wih = (const float*)d_in[2];
  const float* bih = (const float*)d_in[3];
  const float* Whh = (const float*)d_in[4];
  const float* bhh = (const float*)d_in[5];
  const float* ow1 = (const float*)d_in[6];
  const float* ob1 = (const float*)d_in[7];
  const float* ow2 = (const float*)d_in[8];
  const float* ob2 = (const float*)d_in[9];
  const float* l1w = (const float*)d_in[10];
  const float* l1b = (const float*)d_in[11];
  const float* muw = (const float*)d_in[12];
  const float* mub = (const float*)d_in[13];
  const float* sw1 = (const float*)d_in[14];
  const float* sb1 = (const float*)d_in[15];
  const float* sw2 = (const float*)d_in[16];
  const float* sb2 = (const float*)d_in[17];
  float* ws  = (float*)d_ws;
  float* out = (float*)d_out;

  hipFuncSetAttribute((const void*)odernn_main,
                      hipFuncAttributeMaxDynamicSharedMemorySize, SMEM_BYTES);

  prep_transpose<<<WS_TOT / NT, NT, 0, stream>>>(Wih, Whh, l1w, sw1, ws);
  odernn_main<<<256, NT, SMEM_BYTES, stream>>>(dt, x, bih, bhh, ow1, ob1, ow2, ob2,
                                               l1b, muw, mub, sb1, sw2, sb2, ws, out);
}

// Round 2
// 5986.205 us; speedup vs baseline: 1.7586x; 1.7586x over previous
//
#include <hip/hip_runtime.h>
#include <math.h>

// ODE-RNN forward: B=1024, T=100, D=32, H=256, MID=50 (padded 64), RK4x4.
// Round 2: 512 threads (8 waves, 2/SIMD), ODE weights in VGPRs, quad-col
// output tiles (few LDS broadcasts), packed float4 global weight streams,
// stride-20 partial slots (conflict-free).

#define NT 512

// ---------------- ws layout (floats), all packed-k float4 ----------------
// Wcat4: [72 g][256 j][4 c]  k=4g+c over concat [x(32); h(256)]
// l1p4 : [64 g][128 j][4 c]
// sw1p4: [64 g][256 j][4 c]
#define WS_WCAT 0
#define WS_L1P  73728
#define WS_SW1  106496
#define WS_TOT  172032

// ---------------- LDS layout (floats) ----------------
#define SM_PR1 0        // 512*20 partial slots
#define SM_PR2 10240    // 512*20
#define SM_H   20480    // [4][256] flat
#define SM_YC  21504    // [4][256] (alias l1o[4][128])
#define SM_AC  22528    // [4][256] (alias sg[4][256])
#define SM_MD  23552    // [4][64]
#define SM_X4  23808    // [4][32]
#define SM_BC  23936    // 256
#define SM_OB1 24192    // 64
#define SM_OB2 24256    // 256
#define SM_L1B 24512    // 128
#define SM_SB1 24640    // 256
#define SM_MUW 24896    // 128
#define SM_SW2 25024    // 256
#define SM_SCL 25280    // 8
#define SM_TOT 25288
#define SMEM_BYTES (SM_TOT * 4)

__device__ __forceinline__ float fma4(float acc, float4 y, float4 w) {
  acc = fmaf(y.x, w.x, acc);
  acc = fmaf(y.y, w.y, acc);
  acc = fmaf(y.z, w.z, acc);
  acc = fmaf(y.w, w.w, acc);
  return acc;
}

__device__ __forceinline__ float tfast(float x) {
  float ax = fabsf(x);
  float e  = __expf(-2.f * ax);
  float t  = (1.f - e) * __builtin_amdgcn_rcpf(1.f + e);
  return copysignf(t, x);
}

__global__ void prep_transpose(const float* __restrict__ Wih,
                               const float* __restrict__ Whh,
                               const float* __restrict__ l1w,
                               const float* __restrict__ sw1,
                               float* __restrict__ ws) {
  int i = blockIdx.x * 256 + threadIdx.x;
  if (i < 73728) {                       // Wcat4
    int g = i >> 10, rem = i & 1023, j = rem >> 2, c = rem & 3;
    int k = 4 * g + c;
    ws[i] = (k < 32) ? Wih[j * 32 + k] : Whh[j * 256 + (k - 32)];
  } else if (i < 106496) {               // l1p4
    int t = i - 73728;
    int g = t >> 9, rem = t & 511, j = rem >> 2, c = rem & 3;
    ws[i] = l1w[j * 256 + 4 * g + c];
  } else if (i < WS_TOT) {               // sw1p4
    int t = i - 106496;
    int g = t >> 10, rem = t & 1023, j = rem >> 2, c = rem & 3;
    ws[i] = sw1[j * 256 + 4 * g + c];
  }
}

__launch_bounds__(NT, 2)
__global__ void odernn_main(const float* __restrict__ dt,
                            const float* __restrict__ x,
                            const float* __restrict__ bih,
                            const float* __restrict__ bhh,
                            const float* __restrict__ ow1,
                            const float* __restrict__ ob1g,
                            const float* __restrict__ ow2,
                            const float* __restrict__ ob2g,
                            const float* __restrict__ l1bg,
                            const float* __restrict__ muwg,
                            const float* __restrict__ mubg,
                            const float* __restrict__ sb1g,
                            const float* __restrict__ sw2g,
                            const float* __restrict__ sb2g,
                            const float* __restrict__ ws,
                            float* __restrict__ out) {
  extern __shared__ __align__(16) float sm[];
  const int tid = threadIdx.x;
  const int wv = tid >> 6, ln = tid & 63;
  const int b0 = blockIdx.x * 4;

  float* prS  = sm + SM_PR1;
  float* prS2 = sm + SM_PR2;
  float* hS   = sm + SM_H;
  float* ycS  = sm + SM_YC;
  float* acS  = sm + SM_AC;
  float* mdS  = sm + SM_MD;
  float* x4S  = sm + SM_X4;
  float* bcS  = sm + SM_BC;
  float* ob1S = sm + SM_OB1;
  float* ob2S = sm + SM_OB2;
  float* l1bS = sm + SM_L1B;
  float* sb1S = sm + SM_SB1;
  float* muwS = sm + SM_MUW;
  float* sw2S = sm + SM_SW2;
  float* sclS = sm + SM_SCL;
  float* l1oS = ycS;
  float* sgS  = acS;

  float4* pr1_4 = (float4*)prS;
  float4* pr2_4 = (float4*)prS2;
  const float4* h44 = (const float4*)hS;   // [4][64]
  const float4* yc44 = (const float4*)ycS; // [4][64]
  const float4* md4 = (const float4*)mdS;  // [4][16]
  const float4* x44 = (const float4*)x4S;  // [4][8]

  const float4* wcat4 = (const float4*)(ws + WS_WCAT); // f4 idx g*256 + j
  const float4* l1w4  = (const float4*)(ws + WS_L1P);  // f4 idx g*128 + j
  const float4* sw14  = (const float4*)(ws + WS_SW1);  // f4 idx g*256 + j

  // ---- persistent ODE weight registers
  float4 w1r[4][4];   // layer1: [n][g], neuron 4*q1+n, k = kc1*16+4g+c
  float4 w2r[4][4];   // layer2: [n][g], col 4*cq2+n,  k = kc2*16+4g+c
  {
    const int q1 = tid & 15, kc1 = (tid >> 4) & 15;
#pragma unroll
    for (int n = 0; n < 4; ++n) {
      int row = 4 * q1 + n;
#pragma unroll
      for (int g = 0; g < 4; ++g) {
        if (row < 50)
          w1r[n][g] = *(const float4*)&ow1[row * 256 + kc1 * 16 + 4 * g];
        else
          w1r[n][g] = make_float4(0.f, 0.f, 0.f, 0.f);
      }
    }
  }
  {
    const int cq2 = tid & 63, kc2 = (tid >> 6) & 3;
    float w2tmp[4];
#pragma unroll
    for (int n = 0; n < 4; ++n) {
      int col = 4 * cq2 + n;
#pragma unroll
      for (int g = 0; g < 4; ++g) {
#pragma unroll
        for (int c = 0; c < 4; ++c) {
          int k = kc2 * 16 + 4 * g + c;
          w2tmp[c] = (k < 50) ? ow2[col * 50 + k] : 0.f;
        }
        w2r[n][g] = make_float4(w2tmp[0], w2tmp[1], w2tmp[2], w2tmp[3]);
      }
    }
  }

  // ---- one-time staging
  if (tid < 256) {
    bcS[tid]  = bih[tid] + bhh[tid];
    ob2S[tid] = ob2g[tid];
    sb1S[tid] = sb1g[tid];
    sw2S[tid] = sw2g[tid];
  }
  if (tid < 64)  ob1S[tid] = (tid < 50) ? ob1g[tid] : 0.f;
  if (tid < 128) { l1bS[tid] = l1bg[tid]; muwS[tid] = muwg[tid]; }
  hS[tid] = 0.f; hS[tid + 512] = 0.f;
  __syncthreads();

  const float mub = mubg[0], sb2 = sb2g[0];

  for (int t = 0; t < 100; ++t) {
    // ---- stage x tile and per-row scale
    if (tid < 128) {
      int r = tid >> 5, kk = tid & 31;
      x4S[r * 32 + kk] = x[((size_t)(b0 + r) * 100 + t) * 32 + kk];
    }
    if (tid < 4) {
      const float* dp = dt + ((size_t)(b0 + tid) * 100 + t) * 2;
      sclS[tid] = (dp[1] - dp[0]) * (1.f / 24.f);
    }
    __syncthreads();

    // ===== RNN partials: K=288 concat, (jq 64, kc 8), 4 cols x 4 rows
    {
      const int jq = tid & 63, kc = tid >> 6;
      float4 acc0 = make_float4(0, 0, 0, 0), acc1 = acc0, acc2 = acc0, acc3 = acc0;
#pragma unroll
      for (int gg = 0; gg < 9; ++gg) {
        int g = kc * 9 + gg;                         // k = 4g
        float4 w0 = wcat4[g * 256 + 4 * jq + 0];
        float4 w1 = wcat4[g * 256 + 4 * jq + 1];
        float4 w2 = wcat4[g * 256 + 4 * jq + 2];
        float4 w3 = wcat4[g * 256 + 4 * jq + 3];
        float4 y0 = (g < 8) ? x44[0 * 8 + g] : h44[0 * 64 + (g - 8)];
        float4 y1 = (g < 8) ? x44[1 * 8 + g] : h44[1 * 64 + (g - 8)];
        float4 y2 = (g < 8) ? x44[2 * 8 + g] : h44[2 * 64 + (g - 8)];
        float4 y3 = (g < 8) ? x44[3 * 8 + g] : h44[3 * 64 + (g - 8)];
        acc0.x = fma4(acc0.x, y0, w0); acc0.y = fma4(acc0.y, y0, w1);
        acc0.z = fma4(acc0.z, y0, w2); acc0.w = fma4(acc0.w, y0, w3);
        acc1.x = fma4(acc1.x, y1, w0); acc1.y = fma4(acc1.y, y1, w1);
        acc1.z = fma4(acc1.z, y1, w2); acc1.w = fma4(acc1.w, y1, w3);
        acc2.x = fma4(acc2.x, y2, w0); acc2.y = fma4(acc2.y, y2, w1);
        acc2.z = fma4(acc2.z, y2, w2); acc2.w = fma4(acc2.w, y2, w3);
        acc3.x = fma4(acc3.x, y3, w0); acc3.y = fma4(acc3.y, y3, w1);
        acc3.z = fma4(acc3.z, y3, w2); acc3.w = fma4(acc3.w, y3, w3);
      }
      pr1_4[tid * 5 + 0] = acc0;
      pr1_4[tid * 5 + 1] = acc1;
      pr1_4[tid * 5 + 2] = acc2;
      pr1_4[tid * 5 + 3] = acc3;
    }
    __syncthreads();
    // ===== RNN reduce: h += tanh(sum partials + bias)
    {
#pragma unroll
      for (int oo = 0; oo < 2; ++oo) {
        int o = tid + oo * 512;
        int r = o >> 8, j = o & 255;
        int q = j >> 2, n = j & 3;
        float s = bcS[j];
#pragma unroll
        for (int kc = 0; kc < 8; ++kc)
          s += prS[(kc * 64 + q) * 20 + r * 4 + n];
        hS[o] += tfast(s);
      }
    }
    __syncthreads();

    // ===== ODE: 4 RK4 steps, hs = 0.25
    const int q1 = tid & 15, kc1 = (tid >> 4) & 15, h1 = tid >> 8;
    const int cq2 = tid & 63, kc2 = (tid >> 6) & 3, h2 = tid >> 8;
#pragma unroll 1
    for (int os = 0; os < 4; ++os) {
#pragma unroll
      for (int s = 0; s < 4; ++s) {
        // --- layer1 partials: (q1 16, kc1 16, h1 2): 4 neurons x 2 rows x 16 k
        {
          const float4* ysrc = (s == 0) ? h44 : yc44;
          float4 a0 = make_float4(0, 0, 0, 0), a1 = a0;
#pragma unroll
          for (int g = 0; g < 4; ++g) {
            float4 y0 = ysrc[(h1 * 2 + 0) * 64 + kc1 * 4 + g];
            float4 y1 = ysrc[(h1 * 2 + 1) * 64 + kc1 * 4 + g];
            a0.x = fma4(a0.x, y0, w1r[0][g]); a0.y = fma4(a0.y, y0, w1r[1][g]);
            a0.z = fma4(a0.z, y0, w1r[2][g]); a0.w = fma4(a0.w, y0, w1r[3][g]);
            a1.x = fma4(a1.x, y1, w1r[0][g]); a1.y = fma4(a1.y, y1, w1r[1][g]);
            a1.z = fma4(a1.z, y1, w1r[2][g]); a1.w = fma4(a1.w, y1, w1r[3][g]);
          }
          pr1_4[tid * 5 + 0] = a0;
          pr1_4[tid * 5 + 1] = a1;
        }
        __syncthreads();
        // --- layer1 reduce + tanh -> mdS
        if (tid < 256) {
          int r = tid >> 6, n = tid & 63;
          int hh = r >> 1, rr = r & 1, q = n >> 2, nn = n & 3;
          float sv = ob1S[n];
#pragma unroll
          for (int kc = 0; kc < 16; ++kc)
            sv += prS[(hh * 256 + kc * 16 + q) * 20 + rr * 4 + nn];
          mdS[r * 64 + n] = tfast(sv);
        }
        __syncthreads();
        // --- layer2 partials: (cq2 64, kc2 4, h2 2): 4 cols x 2 rows x 16 k
        {
          float4 b0v = make_float4(0, 0, 0, 0), b1v = b0v;
#pragma unroll
          for (int g = 0; g < 4; ++g) {
            float4 m0 = md4[(h2 * 2 + 0) * 16 + kc2 * 4 + g];
            float4 m1 = md4[(h2 * 2 + 1) * 16 + kc2 * 4 + g];
            b0v.x = fma4(b0v.x, m0, w2r[0][g]); b0v.y = fma4(b0v.y, m0, w2r[1][g]);
            b0v.z = fma4(b0v.z, m0, w2r[2][g]); b0v.w = fma4(b0v.w, m0, w2r[3][g]);
            b1v.x = fma4(b1v.x, m1, w2r[0][g]); b1v.y = fma4(b1v.y, m1, w2r[1][g]);
            b1v.z = fma4(b1v.z, m1, w2r[2][g]); b1v.w = fma4(b1v.w, m1, w2r[3][g]);
          }
          pr2_4[tid * 5 + 0] = b0v;
          pr2_4[tid * 5 + 1] = b1v;
        }
        __syncthreads();
        // --- layer2 reduce + RK4 state update
        {
#pragma unroll
          for (int oo = 0; oo < 2; ++oo) {
            int o = tid + oo * 512;
            int r = o >> 8, j = o & 255;
            int hh = r >> 1, rr = r & 1, q = j >> 2, nn = j & 3;
            float sv = ob2S[j];
#pragma unroll
            for (int kc = 0; kc < 4; ++kc)
              sv += prS2[(hh * 256 + kc * 64 + q) * 20 + rr * 4 + nn];
            float kv = sv * sclS[r];
            if (s == 0)      { acS[o] = kv;        ycS[o] = hS[o] + 0.125f * kv; }
            else if (s == 1) { acS[o] += 2.f * kv; ycS[o] = hS[o] + 0.125f * kv; }
            else if (s == 2) { acS[o] += 2.f * kv; ycS[o] = hS[o] + 0.25f  * kv; }
            else             { hS[o] += (0.25f / 6.f) * (acS[o] + kv); }
          }
        }
        __syncthreads();
      }
    }

    // ===== heads
    // l1 partials: (cq 32, kc 16): 4 cols x 4 rows x 16 k  -> prS
    {
      const int cq = tid & 31, kc = tid >> 5;
      float4 c0 = make_float4(0, 0, 0, 0), c1 = c0, c2 = c0, c3 = c0;
#pragma unroll
      for (int g = 0; g < 4; ++g) {
        int kg = kc * 4 + g;
        float4 w0 = l1w4[kg * 128 + 4 * cq + 0];
        float4 w1 = l1w4[kg * 128 + 4 * cq + 1];
        float4 w2 = l1w4[kg * 128 + 4 * cq + 2];
        float4 w3 = l1w4[kg * 128 + 4 * cq + 3];
        float4 y0 = h44[0 * 64 + kg], y1 = h44[1 * 64 + kg];
        float4 y2 = h44[2 * 64 + kg], y3 = h44[3 * 64 + kg];
        c0.x = fma4(c0.x, y0, w0); c0.y = fma4(c0.y, y0, w1);
        c0.z = fma4(c0.z, y0, w2); c0.w = fma4(c0.w, y0, w3);
        c1.x = fma4(c1.x, y1, w0); c1.y = fma4(c1.y, y1, w1);
        c1.z = fma4(c1.z, y1, w2); c1.w = fma4(c1.w, y1, w3);
        c2.x = fma4(c2.x, y2, w0); c2.y = fma4(c2.y, y2, w1);
        c2.z = fma4(c2.z, y2, w2); c2.w = fma4(c2.w, y2, w3);
        c3.x = fma4(c3.x, y3, w0); c3.y = fma4(c3.y, y3, w1);
        c3.z = fma4(c3.z, y3, w2); c3.w = fma4(c3.w, y3, w3);
      }
      pr1_4[tid * 5 + 0] = c0;
      pr1_4[tid * 5 + 1] = c1;
      pr1_4[tid * 5 + 2] = c2;
      pr1_4[tid * 5 + 3] = c3;
    }
    // sig1 partials: (cq 64, kc 8): 4 cols x 4 rows x 32 k  -> prS2
    {
      const int cq = tid & 63, kc = tid >> 6;
      float4 d0 = make_float4(0, 0, 0, 0), d1 = d0, d2 = d0, d3 = d0;
#pragma unroll
      for (int g = 0; g < 8; ++g) {
        int kg = kc * 8 + g;
        float4 w0 = sw14[kg * 256 + 4 * cq + 0];
        float4 w1 = sw14[kg * 256 + 4 * cq + 1];
        float4 w2 = sw14[kg * 256 + 4 * cq + 2];
        float4 w3 = sw14[kg * 256 + 4 * cq + 3];
        float4 y0 = h44[0 * 64 + kg], y1 = h44[1 * 64 + kg];
        float4 y2 = h44[2 * 64 + kg], y3 = h44[3 * 64 + kg];
        d0.x = fma4(d0.x, y0, w0); d0.y = fma4(d0.y, y0, w1);
        d0.z = fma4(d0.z, y0, w2); d0.w = fma4(d0.w, y0, w3);
        d1.x = fma4(d1.x, y1, w0); d1.y = fma4(d1.y, y1, w1);
        d1.z = fma4(d1.z, y1, w2); d1.w = fma4(d1.w, y1, w3);
        d2.x = fma4(d2.x, y2, w0); d2.y = fma4(d2.y, y2, w1);
        d2.z = fma4(d2.z, y2, w2); d2.w = fma4(d2.w, y2, w3);
        d3.x = fma4(d3.x, y3, w0); d3.y = fma4(d3.y, y3, w1);
        d3.z = fma4(d3.z, y3, w2); d3.w = fma4(d3.w, y3, w3);
      }
      pr2_4[tid * 5 + 0] = d0;
      pr2_4[tid * 5 + 1] = d1;
      pr2_4[tid * 5 + 2] = d2;
      pr2_4[tid * 5 + 3] = d3;
    }
    __syncthreads();
    // l1 reduce -> relu -> l1oS
    {
      int r = tid >> 7, j2 = tid & 127;
      int q = j2 >> 2, nn = j2 & 3;
      float s = l1bS[j2];
#pragma unroll
      for (int kc = 0; kc < 16; ++kc)
        s += prS[(kc * 32 + q) * 20 + r * 4 + nn];
      l1oS[r * 128 + j2] = fmaxf(s, 0.f);
    }
    // sig1 reduce -> tanh -> sgS
    {
#pragma unroll
      for (int oo = 0; oo < 2; ++oo) {
        int o = tid + oo * 512;
        int r = o >> 8, j = o & 255;
        int q = j >> 2, nn = j & 3;
        float s = sb1S[j];
#pragma unroll
        for (int kc = 0; kc < 8; ++kc)
          s += prS2[(kc * 64 + q) * 20 + r * 4 + nn];
        sgS[o] = tfast(s);
      }
    }
    __syncthreads();
    // final dot-products: wave wv: row = wv&3, head = wv>>2
    {
      const int r = wv & 3;
      if (wv < 4) {
        float pm = l1oS[r * 128 + ln] * muwS[ln]
                 + l1oS[r * 128 + 64 + ln] * muwS[64 + ln];
#pragma unroll
        for (int off = 32; off > 0; off >>= 1) pm += __shfl_down(pm, off);
        if (ln == 0) out[(size_t)(b0 + r) * 100 + t] = pm + mub;
      } else {
        float ps = sgS[r * 256 + ln] * sw2S[ln]
                 + sgS[r * 256 + 64 + ln] * sw2S[64 + ln]
                 + sgS[r * 256 + 128 + ln] * sw2S[128 + ln]
                 + sgS[r * 256 + 192 + ln] * sw2S[192 + ln];
#pragma unroll
        for (int off = 32; off > 0; off >>= 1) ps += __shfl_down(ps, off);
        if (ln == 0) {
          float z = ps + sb2;
          float sp = fmaxf(z, 0.f) + log1pf(expf(-fabsf(z)));
          out[(size_t)102400 + (size_t)(b0 + r) * 100 + t] = sp;
        }
      }
    }
    // no barrier needed: next-step staging writes x4S/sclS (disjoint from
    // l1oS/sgS reads above); first write to prS is after the stage barrier.
  }
}

extern "C" void kernel_launch(void* const* d_in, const int* in_sizes, int n_in,
                              void* d_out, int out_size, void* d_ws, size_t ws_size,
                              hipStream_t stream) {
  const float* dt  = (const float*)d_in[0];
  const float* x   = (const float*)d_in[1];
  const float* Wih = (const float*)d_in[2];
  const float* bih = (const float*)d_in[3];
  const float* Whh = (const float*)d_in[4];
  const float* bhh = (const float*)d_in[5];
  const float* ow1 = (const float*)d_in[6];
  const float* ob1 = (const float*)d_in[7];
  const float* ow2 = (const float*)d_in[8];
  const float* ob2 = (const float*)d_in[9];
  const float* l1w = (const float*)d_in[10];
  const float* l1b = (const float*)d_in[11];
  const float* muw = (const float*)d_in[12];
  const float* mub = (const float*)d_in[13];
  const float* sw1 = (const float*)d_in[14];
  const float* sb1 = (const float*)d_in[15];
  const float* sw2 = (const float*)d_in[16];
  const float* sb2 = (const float*)d_in[17];
  float* ws  = (float*)d_ws;
  float* out = (float*)d_out;

  hipFuncSetAttribute((const void*)odernn_main,
                      hipFuncAttributeMaxDynamicSharedMemorySize, SMEM_BYTES);

  prep_transpose<<<WS_TOT / 256, 256, 0, stream>>>(Wih, Whh, l1w, sw1, ws);
  odernn_main<<<256, NT, SMEM_BYTES, stream>>>(dt, x, bih, bhh, ow1, ob1, ow2, ob2,
                                               l1b, muw, mub, sb1, sw2, sb2, ws, out);
}